// Round 1
// 190.861 us; speedup vs baseline: 1.0004x; 1.0004x over previous
//
#include <hip/hip_runtime.h>

// Problem constants (from reference)
#define B_ 32
#define S_ 512
#define H_ 768
#define C_ 32      // N_COLS
#define L_ 16      // MAX_HLEN
#define NCOMB 132  // 11 match * 6 type * 2 token_type combined-aux rows

typedef float f4 __attribute__((ext_vector_type(4)));  // native vector (nontemporal-store capable)

__device__ __forceinline__ f4 ld4(const float* p) {
    return *reinterpret_cast<const f4*>(p);
}

// ---------------------------------------------------------------------------
// Precompute kernel: comb[(mt*6+ty)*2+tt] = match_emb[mt] + type_emb[ty] + tok_type_emb[tt]
// 132 rows x 768 floats = 405 KB into d_ws. One wave per row, 12 floats/lane.
// Replaces 3 per-token table gathers (150 MB of L2 traffic) with 1 (50 MB).
// ---------------------------------------------------------------------------
__global__ __launch_bounds__(64) void combine_aux_kernel(
    const float* __restrict__ tok_type_emb,  // [2,H]
    const float* __restrict__ match_emb,     // [11,H]
    const float* __restrict__ type_emb,      // [6,H]
    float* __restrict__ comb)                // [132,H]
{
    const int row = blockIdx.x;        // row = mt*12 + ty*2 + tt
    const int mt  = row / 12;
    const int rem = row - mt * 12;
    const int ty  = rem >> 1;
    const int tt  = rem & 1;
    const int h   = (int)threadIdx.x << 2;
    const float* pm = match_emb    + mt * H_;
    const float* pt = type_emb     + ty * H_;
    const float* pk = tok_type_emb + tt * H_;
    float* po = comb + (size_t)row * H_;
    #pragma unroll
    for (int c = 0; c < 3; ++c) {
        const int o = h + c * 256;
        f4 v = ld4(pm + o) + ld4(pt + o) + ld4(pk + o);
        *reinterpret_cast<f4*>(po + o) = v;
    }
}

// ---------------------------------------------------------------------------
// Main kernel. One WAVE (64 lanes) per token; 12 floats/lane (3 x float4).
// 256-thread blocks = 4 tokens/block -> grid = B*S/4 = 4096. Single pass,
// no __syncthreads: LayerNorm reduce is a wave shfl_xor butterfly.
// USE_COMB=1: aux embeddings come pre-summed from the 132-row ws table.
// ---------------------------------------------------------------------------
template<int USE_COMB>
__global__ __launch_bounds__(256) void bert_emb_kernel(
    const int* __restrict__ input_ids,       // [B,S]
    const int* __restrict__ header_ids,      // [B,C,L]
    const int* __restrict__ token_type_ids,  // [B,S]
    const int* __restrict__ match_type_ids,  // [B,S]
    const int* __restrict__ type_idx,        // [B,S]
    const int* __restrict__ col_pos,         // [B,C]
    const int* __restrict__ col_idx,         // [B,C]
    const int* __restrict__ header_len,      // [B,C]
    const float* __restrict__ word_emb,      // [VOCAB,H] f32
    const float* __restrict__ pos_emb,       // [MAX_POS,H]
    const float* __restrict__ tok_type_emb,  // [2,H]
    const float* __restrict__ match_emb,     // [11,H]
    const float* __restrict__ type_emb,      // [6,H]
    const float* __restrict__ ln_w,          // [H]
    const float* __restrict__ ln_b,          // [H]
    const float* __restrict__ comb,          // [132,H] fused aux (ws) or null
    float* __restrict__ out)                 // [B,S,H] f32
{
    const int tok  = blockIdx.x * 4 + (threadIdx.x >> 6);  // 0..16383
    const int lane = threadIdx.x & 63;
    const int b    = tok >> 9;
    const int s    = tok & (S_ - 1);

    // Hoist the word id load: the random word_emb gather is the longest
    // latency chain, get its address ready before the ballot/branch.
    const int wid = input_ids[tok];

    // ---- override check: one ballot over the low 32 lanes (col_pos distinct per row)
    const int cp = col_pos[(b << 5) + (lane & 31)];
    unsigned long long m = __ballot(cp == s) & 0xffffffffULL;
    int use_pool = 0, ci = 0, hlen = 0;
    if (m) {
        const int cm = __ffsll(m) - 1;
        ci   = col_idx[(b << 5) + cm];
        hlen = header_len[(b << 5) + ci];
        use_pool = (hlen > 0);
    }

    const int h = lane << 2;   // lane owns h, h+256, h+512 (3 x float4)
    f4 a0, a1, a2;

    // ---- word vector: gather (common) or variable-length mean pool (wave-uniform)
    if (use_pool) {
        a0 = (f4){0,0,0,0}; a1 = (f4){0,0,0,0}; a2 = (f4){0,0,0,0};
        const int* hid = header_ids + ((b << 5) + ci) * L_;
        for (int l = 0; l < hlen; ++l) {
            const float* r = word_emb + (size_t)hid[l] * H_ + h;
            a0 += ld4(r); a1 += ld4(r + 256); a2 += ld4(r + 512);
        }
        const float inv = 1.0f / (float)hlen;
        a0 *= inv; a1 *= inv; a2 *= inv;
    } else {
        const float* r = word_emb + (size_t)wid * H_ + h;
        a0 = ld4(r); a1 = ld4(r + 256); a2 = ld4(r + 512);
    }

    // ---- positional embedding (L2-resident, streams with s)
    {
        const float* r = pos_emb + s * H_ + h;
        a0 += ld4(r); a1 += ld4(r + 256); a2 += ld4(r + 512);
    }

    // ---- auxiliary embeddings
    if (USE_COMB) {
        // one fused row instead of three table gathers
        const int row = match_type_ids[tok] * 12 + type_idx[tok] * 2 + token_type_ids[tok];
        const float* r = comb + (size_t)row * H_ + h;
        a0 += ld4(r); a1 += ld4(r + 256); a2 += ld4(r + 512);
    } else {
        {
            const float* r = tok_type_emb + token_type_ids[tok] * H_ + h;
            a0 += ld4(r); a1 += ld4(r + 256); a2 += ld4(r + 512);
        }
        {
            const float* r = match_emb + match_type_ids[tok] * H_ + h;
            a0 += ld4(r); a1 += ld4(r + 256); a2 += ld4(r + 512);
        }
        {
            const float* r = type_emb + type_idx[tok] * H_ + h;
            a0 += ld4(r); a1 += ld4(r + 256); a2 += ld4(r + 512);
        }
    }

    // ---- LayerNorm over H=768: wave butterfly (all lanes end with totals)
    float s1 = a0.x+a0.y+a0.z+a0.w + a1.x+a1.y+a1.z+a1.w + a2.x+a2.y+a2.z+a2.w;
    float s2 = a0.x*a0.x+a0.y*a0.y+a0.z*a0.z+a0.w*a0.w
             + a1.x*a1.x+a1.y*a1.y+a1.z*a1.z+a1.w*a1.w
             + a2.x*a2.x+a2.y*a2.y+a2.z*a2.z+a2.w*a2.w;
    #pragma unroll
    for (int off = 32; off > 0; off >>= 1) {
        s1 += __shfl_xor(s1, off);
        s2 += __shfl_xor(s2, off);
    }
    const float mean = s1 * (1.0f / H_);
    float var = fmaxf(s2 * (1.0f / H_) - mean * mean, 0.0f);
    const float rstd = rsqrtf(var + 1e-12f);

    // ---- scale/shift, non-temporal store (output never re-read; keep L2/L3 for gathers)
    float* op = out + (size_t)tok * H_ + h;
    {
        f4 w = ld4(ln_w + h), c = ld4(ln_b + h);
        f4 o = (a0 - mean) * rstd * w + c;
        __builtin_nontemporal_store(o, reinterpret_cast<f4*>(op));
    }
    {
        f4 w = ld4(ln_w + h + 256), c = ld4(ln_b + h + 256);
        f4 o = (a1 - mean) * rstd * w + c;
        __builtin_nontemporal_store(o, reinterpret_cast<f4*>(op + 256));
    }
    {
        f4 w = ld4(ln_w + h + 512), c = ld4(ln_b + h + 512);
        f4 o = (a2 - mean) * rstd * w + c;
        __builtin_nontemporal_store(o, reinterpret_cast<f4*>(op + 512));
    }
}

extern "C" void kernel_launch(void* const* d_in, const int* in_sizes, int n_in,
                              void* d_out, int out_size, void* d_ws, size_t ws_size,
                              hipStream_t stream) {
    const int* input_ids      = (const int*)d_in[0];
    const int* header_ids     = (const int*)d_in[1];
    const int* token_type_ids = (const int*)d_in[2];
    const int* match_type_ids = (const int*)d_in[3];
    const int* type_idx       = (const int*)d_in[4];
    const int* col_pos        = (const int*)d_in[5];
    const int* col_idx        = (const int*)d_in[6];
    const int* header_len     = (const int*)d_in[7];
    const float* word_emb     = (const float*)d_in[8];
    const float* pos_emb      = (const float*)d_in[9];
    const float* tok_type_emb = (const float*)d_in[10];
    const float* match_emb    = (const float*)d_in[11];
    const float* type_emb     = (const float*)d_in[12];
    const float* ln_w         = (const float*)d_in[13];
    const float* ln_b         = (const float*)d_in[14];
    float* out = (float*)d_out;

    const size_t comb_bytes = (size_t)NCOMB * H_ * sizeof(float);  // 405 KB
    if (d_ws != nullptr && ws_size >= comb_bytes) {
        float* comb = (float*)d_ws;
        combine_aux_kernel<<<NCOMB, 64, 0, stream>>>(tok_type_emb, match_emb, type_emb, comb);
        bert_emb_kernel<1><<<(B_ * S_) / 4, 256, 0, stream>>>(
            input_ids, header_ids, token_type_ids, match_type_ids, type_idx,
            col_pos, col_idx, header_len, word_emb, pos_emb, tok_type_emb,
            match_emb, type_emb, ln_w, ln_b, comb, out);
    } else {
        bert_emb_kernel<0><<<(B_ * S_) / 4, 256, 0, stream>>>(
            input_ids, header_ids, token_type_ids, match_type_ids, type_idx,
            col_pos, col_idx, header_len, word_emb, pos_emb, tok_type_emb,
            match_emb, type_emb, ln_w, ln_b, nullptr, out);
    }
}